// Round 7
// baseline (621.417 us; speedup 1.0000x reference)
//
#include <hip/hip_runtime.h>
#include <hip/hip_bf16.h>
#include <math.h>

#define D_MODEL    1024
#define EXPERT_DIM 4096
#define N_EXPERTS  8
#define N_TOKENS   4096
#define M_TILE     128
#define MAX_TILES  40

typedef __attribute__((ext_vector_type(8))) short short8;
typedef __attribute__((ext_vector_type(4))) float f32x4;

// workspace byte offsets
#define OFF_PROBS   0u
#define OFF_EXP     131072u
#define OFF_GATE    147456u
#define OFF_CNT     163840u     // 8 i32
#define OFF_CUR     163872u     // 8 i32
#define OFF_SIMP    163904u     // 8 f32
#define OFF_OFFS    163936u     // 9 i32
#define OFF_NT      163976u     // 1 i32
#define OFF_TE      164096u     // 40 i32
#define OFF_TR      164352u     // 40 i32
#define OFF_BUCKET  164608u     // 4096 i32
#define OFF_XB      262144u     // 4096*1024 bf16 = 8 MiB
#define OFF_H       8650752u    // 4096*4096 bf16 = 32 MiB

#define GLOAD_LDS16(gp, lp) \
  __builtin_amdgcn_global_load_lds((const __attribute__((address_space(1))) void*)(gp), \
                                   (__attribute__((address_space(3))) void*)(lp), 16, 0, 0)

static __device__ __forceinline__ ushort f2b(float f) {
  union { __hip_bfloat16 h; ushort u; } c;
  c.h = __float2bfloat16(f);
  return c.u;
}

static __device__ __forceinline__ short8 cvt8(float4 a, float4 b) {
  short8 r;
  r[0] = (short)f2b(a.x); r[1] = (short)f2b(a.y);
  r[2] = (short)f2b(a.z); r[3] = (short)f2b(a.w);
  r[4] = (short)f2b(b.x); r[5] = (short)f2b(b.y);
  r[6] = (short)f2b(b.z); r[7] = (short)f2b(b.w);
  return r;
}

// ---------------- gating (fp32, exact argmax) + x -> bf16 cast ----------------
__global__ __launch_bounds__(256) void gate_kernel(
    const float* __restrict__ x, const float* __restrict__ gw,
    float* __restrict__ probs, int* __restrict__ tok_e,
    float* __restrict__ tok_g, int* __restrict__ cnt,
    ushort* __restrict__ xb) {
  int token = (blockIdx.x * blockDim.x + threadIdx.x) >> 6;
  int lane = threadIdx.x & 63;
  if (token >= N_TOKENS) return;
  const float* xr = x + (size_t)token * D_MODEL;
  float xv[16];
#pragma unroll
  for (int i = 0; i < 16; ++i) xv[i] = xr[lane + 64 * i];
  ushort* xo = xb + (size_t)token * D_MODEL;
#pragma unroll
  for (int i = 0; i < 16; ++i) xo[lane + 64 * i] = f2b(xv[i]);
  float logit[N_EXPERTS];
#pragma unroll
  for (int e = 0; e < N_EXPERTS; ++e) {
    const float* g = gw + e * D_MODEL;
    float s = 0.f;
#pragma unroll
    for (int i = 0; i < 16; ++i) s = fmaf(xv[i], g[lane + 64 * i], s);
#pragma unroll
    for (int m = 32; m; m >>= 1) s += __shfl_xor(s, m, 64);
    logit[e] = s;
  }
  if (lane == 0) {
    float mx = logit[0]; int arg = 0;
#pragma unroll
    for (int e = 1; e < N_EXPERTS; ++e)
      if (logit[e] > mx) { mx = logit[e]; arg = e; }
    float pe[N_EXPERTS]; float den = 0.f;
#pragma unroll
    for (int e = 0; e < N_EXPERTS; ++e) { pe[e] = __expf(logit[e] - mx); den += pe[e]; }
    float inv = 1.f / den;
#pragma unroll
    for (int e = 0; e < N_EXPERTS; ++e) probs[token * N_EXPERTS + e] = pe[e] * inv;
    tok_e[token] = arg;
    tok_g[token] = pe[arg] * inv;
    atomicAdd(&cnt[arg], 1);
  }
}

__global__ __launch_bounds__(256) void imp_kernel(
    const float* __restrict__ probs, float* __restrict__ simp) {
  int row = blockIdx.x * 256 + threadIdx.x;
  const float4* p = (const float4*)(probs + (size_t)row * N_EXPERTS);
  float4 a = p[0], b = p[1];
  float v[8] = {a.x, a.y, a.z, a.w, b.x, b.y, b.z, b.w};
#pragma unroll
  for (int m = 32; m; m >>= 1)
#pragma unroll
    for (int i = 0; i < 8; ++i) v[i] += __shfl_xor(v[i], m, 64);
  if ((threadIdx.x & 63) == 0)
#pragma unroll
    for (int i = 0; i < 8; ++i) atomicAdd(&simp[i], v[i]);
}

__global__ void plan_kernel(
    const int* __restrict__ cnt, const float* __restrict__ simp,
    int* __restrict__ offs, int* __restrict__ ntiles,
    int* __restrict__ tile_e, int* __restrict__ tile_r0,
    float* __restrict__ aux_out) {
  if (threadIdx.x == 0 && blockIdx.x == 0) {
    int o = 0, nt = 0; float aux = 0.f;
    for (int e = 0; e < N_EXPERTS; ++e) {
      offs[e] = o;
      int c = cnt[e];
      int m = (c + M_TILE - 1) / M_TILE;
      for (int i = 0; i < m; ++i) { tile_e[nt] = e; tile_r0[nt] = i * M_TILE; ++nt; }
      aux += (float)c * simp[e];
      o += c;
    }
    offs[N_EXPERTS] = o;
    *ntiles = nt;
    *aux_out = aux * (1.f / ((float)N_TOKENS * (float)N_TOKENS)) * N_EXPERTS * 0.01f;
  }
}

__global__ __launch_bounds__(256) void scatter_kernel(
    const int* __restrict__ tok_e, int* __restrict__ cursor,
    const int* __restrict__ offs, int* __restrict__ bucket) {
  int n = blockIdx.x * blockDim.x + threadIdx.x;
  if (n >= N_TOKENS) return;
  int e = tok_e[n];
  int p = atomicAdd(&cursor[e], 1);
  bucket[offs[e] + p] = n;
}

// ---- GEMM1: 128x64 tile, 256 thr. A bf16 via global_load_lds (dbuf LDS,
// swizzled). B (w1,w3 fp32) loaded DIRECTLY global->VGPR per-fragment,
// reg-double-buffered 1 K-step ahead; cvt->bf16 at consume. One barrier/step;
// barrier's vmcnt drain lands after MFMA so B loads overlap compute. ----
__global__ __launch_bounds__(256, 2) void gemm1_kernel(
    const ushort* __restrict__ xb, const float* __restrict__ w1,
    const float* __restrict__ w3, const int* __restrict__ ntiles,
    const int* __restrict__ tile_e, const int* __restrict__ tile_r0,
    const int* __restrict__ offs, const int* __restrict__ bucket,
    ushort* __restrict__ H) {
  // nwg = 64 f-panels * 40 tiles = 2560; XCD chunk 320, m-fastest
  int bid = blockIdx.x;
  int wgid = (bid & 7) * 320 + (bid >> 3);
  int fi = wgid / MAX_TILES;
  int tile = wgid % MAX_TILES;
  if (tile >= *ntiles) return;
  int e = tile_e[tile], r0 = tile_r0[tile];
  int base = offs[e], cnt = offs[e + 1] - base;
  int f0 = fi * 64;

  __shared__ ushort As[2][128 * 64];   // 32 KB total

  int tid = threadIdx.x;
  int w = tid >> 6, l = tid & 63;
  int wm = w >> 1, wn = w & 1;

  // A staging ptrs (pre-swizzled source col, linear LDS dest)
  const ushort* aptr[4];
#pragma unroll
  for (int c = 0; c < 4; ++c) {
    int r = c * 32 + w * 8 + (l >> 3);
    int rr = min(r0 + r, cnt - 1);
    aptr[c] = xb + (size_t)bucket[base + rr] * D_MODEL + ((l & 7) ^ (l >> 3)) * 8;
  }
  // B lane base: row = f0 + wn*32 + (l&15), k-slice (l>>4)*8
  const float* b1lane = w1 + ((size_t)e * EXPERT_DIM + f0 + wn * 32 + (l & 15)) * D_MODEL + (l >> 4) * 8;
  const float* b3lane = w3 + ((size_t)e * EXPERT_DIM + f0 + wn * 32 + (l & 15)) * D_MODEL + (l >> 4) * 8;

  f32x4 accU[4][2], accV[4][2];
#pragma unroll
  for (int i = 0; i < 4; ++i)
#pragma unroll
    for (int j = 0; j < 2; ++j) { accU[i][j] = (f32x4)0.f; accV[i][j] = (f32x4)0.f; }

  float4 c1a[8], c3a[8], c1b[8], c3b[8];

#define STAGE_A1(kk, buf) \
  { _Pragma("unroll") \
    for (int c = 0; c < 4; ++c) \
      GLOAD_LDS16(aptr[c] + (kk) * 64, &As[buf][(c * 32 + w * 8) * 64]); }

#define LOAD_B1(c1, c3, kk) \
  { const float* bp1 = b1lane + (kk) * 64; \
    const float* bp3 = b3lane + (kk) * 64; \
    _Pragma("unroll") \
    for (int j = 0; j < 2; ++j) { \
      _Pragma("unroll") \
      for (int ks = 0; ks < 2; ++ks) { \
        size_t off = (size_t)j * 16 * D_MODEL + ks * 32; \
        c1[(j * 2 + ks) * 2 + 0] = *(const float4*)(bp1 + off); \
        c1[(j * 2 + ks) * 2 + 1] = *(const float4*)(bp1 + off + 4); \
        c3[(j * 2 + ks) * 2 + 0] = *(const float4*)(bp3 + off); \
        c3[(j * 2 + ks) * 2 + 1] = *(const float4*)(bp3 + off + 4); \
      } } }

#define MFMA_PHASE1(buf, c1, c3) \
  { _Pragma("unroll") \
    for (int ks = 0; ks < 2; ++ks) { \
      int acol = (ks * 32 + (l >> 4) * 8) ^ ((l & 7) << 3); \
      short8 af[4]; \
      _Pragma("unroll") \
      for (int i = 0; i < 4; ++i) \
        af[i] = *(const short8*)&As[buf][(wm * 64 + i * 16 + (l & 15)) * 64 + acol]; \
      _Pragma("unroll") \
      for (int j = 0; j < 2; ++j) { \
        int f = (j * 2 + ks) * 2; \
        short8 b1v = cvt8(c1[f], c1[f + 1]); \
        short8 b3v = cvt8(c3[f], c3[f + 1]); \
        _Pragma("unroll") \
        for (int i = 0; i < 4; ++i) { \
          accU[i][j] = __builtin_amdgcn_mfma_f32_16x16x32_bf16(af[i], b1v, accU[i][j], 0, 0, 0); \
          accV[i][j] = __builtin_amdgcn_mfma_f32_16x16x32_bf16(af[i], b3v, accV[i][j], 0, 0, 0); \
        } } } }

  STAGE_A1(0, 0);
  LOAD_B1(c1a, c3a, 0);
  __syncthreads();
  for (int kk = 0; kk < 8; ++kk) {
    int k0 = kk * 2;
    STAGE_A1(k0 + 1, 1);
    LOAD_B1(c1b, c3b, k0 + 1);
    MFMA_PHASE1(0, c1a, c3a);
    __syncthreads();
    if (kk < 7) {
      STAGE_A1(k0 + 2, 0);
      LOAD_B1(c1a, c3a, k0 + 2);
    }
    MFMA_PHASE1(1, c1b, c3b);
    __syncthreads();
  }

  // epilogue: h = silu(u)*v -> bf16 H
#pragma unroll
  for (int i = 0; i < 4; ++i)
#pragma unroll
    for (int q = 0; q < 4; ++q) {
      int m_loc = wm * 64 + i * 16 + (l >> 4) * 4 + q;
      if (r0 + m_loc < cnt) {
        size_t rowb = (size_t)(base + r0 + m_loc) * EXPERT_DIM + f0 + wn * 32 + (l & 15);
#pragma unroll
        for (int j = 0; j < 2; ++j) {
          float uu = accU[i][j][q], vv = accV[i][j][q];
          float hh = uu / (1.f + __expf(-uu)) * vv;
          H[rowb + j * 16] = f2b(hh);
        }
      }
    }
#undef STAGE_A1
#undef LOAD_B1
#undef MFMA_PHASE1
}

// ---- GEMM2: 128x64 tile, same skeleton, K=4096 (64 steps), direct gated out ----
__global__ __launch_bounds__(256, 2) void gemm2_kernel(
    const ushort* __restrict__ H, const float* __restrict__ w2,
    const int* __restrict__ ntiles, const int* __restrict__ tile_e,
    const int* __restrict__ tile_r0, const int* __restrict__ offs,
    const int* __restrict__ bucket, const float* __restrict__ tok_g,
    float* __restrict__ out) {
  // nwg = 16 d-panels * 40 = 640; XCD chunk 80, m-fastest
  int bid = blockIdx.x;
  int wgid = (bid & 7) * 80 + (bid >> 3);
  int di = wgid / MAX_TILES;
  int tile = wgid % MAX_TILES;
  if (tile >= *ntiles) return;
  int e = tile_e[tile], r0 = tile_r0[tile];
  int base = offs[e], cnt = offs[e + 1] - base;
  int d0 = di * 64;

  __shared__ ushort As[2][128 * 64];   // 32 KB

  int tid = threadIdx.x;
  int w = tid >> 6, l = tid & 63;
  int wm = w >> 1, wn = w & 1;

  const ushort* aptr[4];
#pragma unroll
  for (int c = 0; c < 4; ++c) {
    int r = c * 32 + w * 8 + (l >> 3);
    int rr = min(r0 + r, cnt - 1);
    aptr[c] = H + (size_t)(base + rr) * EXPERT_DIM + ((l & 7) ^ (l >> 3)) * 8;
  }
  const float* b2lane = w2 + ((size_t)e * D_MODEL + d0 + wn * 32 + (l & 15)) * EXPERT_DIM + (l >> 4) * 8;

  f32x4 acc[4][2];
#pragma unroll
  for (int i = 0; i < 4; ++i)
#pragma unroll
    for (int j = 0; j < 2; ++j) acc[i][j] = (f32x4)0.f;

  float4 ca[8], cb[8];

#define STAGE_A2(kk, buf) \
  { _Pragma("unroll") \
    for (int c = 0; c < 4; ++c) \
      GLOAD_LDS16(aptr[c] + (kk) * 64, &As[buf][(c * 32 + w * 8) * 64]); }

#define LOAD_B2(cc, kk) \
  { const float* bp = b2lane + (kk) * 64; \
    _Pragma("unroll") \
    for (int j = 0; j < 2; ++j) { \
      _Pragma("unroll") \
      for (int ks = 0; ks < 2; ++ks) { \
        size_t off = (size_t)j * 16 * EXPERT_DIM + ks * 32; \
        cc[(j * 2 + ks) * 2 + 0] = *(const float4*)(bp + off); \
        cc[(j * 2 + ks) * 2 + 1] = *(const float4*)(bp + off + 4); \
      } } }

#define MFMA_PHASE2(buf, cc) \
  { _Pragma("unroll") \
    for (int ks = 0; ks < 2; ++ks) { \
      int acol = (ks * 32 + (l >> 4) * 8) ^ ((l & 7) << 3); \
      short8 af[4]; \
      _Pragma("unroll") \
      for (int i = 0; i < 4; ++i) \
        af[i] = *(const short8*)&As[buf][(wm * 64 + i * 16 + (l & 15)) * 64 + acol]; \
      _Pragma("unroll") \
      for (int j = 0; j < 2; ++j) { \
        int f = (j * 2 + ks) * 2; \
        short8 bv = cvt8(cc[f], cc[f + 1]); \
        _Pragma("unroll") \
        for (int i = 0; i < 4; ++i) \
          acc[i][j] = __builtin_amdgcn_mfma_f32_16x16x32_bf16(af[i], bv, acc[i][j], 0, 0, 0); \
      } } }

  STAGE_A2(0, 0);
  LOAD_B2(ca, 0);
  __syncthreads();
  for (int kk = 0; kk < 32; ++kk) {
    int k0 = kk * 2;
    STAGE_A2(k0 + 1, 1);
    LOAD_B2(cb, k0 + 1);
    MFMA_PHASE2(0, ca);
    __syncthreads();
    if (kk < 31) {
      STAGE_A2(k0 + 2, 0);
      LOAD_B2(ca, k0 + 2);
    }
    MFMA_PHASE2(1, cb);
    __syncthreads();
  }

#pragma unroll
  for (int i = 0; i < 4; ++i)
#pragma unroll
    for (int q = 0; q < 4; ++q) {
      int m_loc = wm * 64 + i * 16 + (l >> 4) * 4 + q;
      if (r0 + m_loc < cnt) {
        int tok = bucket[base + r0 + m_loc];
        float g = tok_g[tok];
        float* op = out + (size_t)tok * D_MODEL + d0 + wn * 32 + (l & 15);
#pragma unroll
        for (int j = 0; j < 2; ++j)
          op[j * 16] = acc[i][j][q] * g;
      }
    }
#undef STAGE_A2
#undef LOAD_B2
#undef MFMA_PHASE2
}

extern "C" void kernel_launch(void* const* d_in, const int* in_sizes, int n_in,
                              void* d_out, int out_size, void* d_ws, size_t ws_size,
                              hipStream_t stream) {
  const float* x  = (const float*)d_in[0];
  const float* gw = (const float*)d_in[1];
  const float* w1 = (const float*)d_in[2];
  const float* w2 = (const float*)d_in[3];
  const float* w3 = (const float*)d_in[4];
  float* out = (float*)d_out;
  char* ws = (char*)d_ws;

  float* probs = (float*)(ws + OFF_PROBS);
  int* tok_e   = (int*)(ws + OFF_EXP);
  float* tok_g = (float*)(ws + OFF_GATE);
  int* cnt     = (int*)(ws + OFF_CNT);
  int* cur     = (int*)(ws + OFF_CUR);
  float* simp  = (float*)(ws + OFF_SIMP);
  int* offs    = (int*)(ws + OFF_OFFS);
  int* ntiles  = (int*)(ws + OFF_NT);
  int* tile_e  = (int*)(ws + OFF_TE);
  int* tile_r0 = (int*)(ws + OFF_TR);
  int* bucket  = (int*)(ws + OFF_BUCKET);
  ushort* xb   = (ushort*)(ws + OFF_XB);
  ushort* H    = (ushort*)(ws + OFF_H);

  hipMemsetAsync(ws + OFF_CNT, 0, 96, stream);  // cnt + cursor + simp
  gate_kernel<<<N_TOKENS / 4, 256, 0, stream>>>(x, gw, probs, tok_e, tok_g, cnt, xb);
  imp_kernel<<<N_TOKENS / 256, 256, 0, stream>>>(probs, simp);
  plan_kernel<<<1, 64, 0, stream>>>(cnt, simp, offs, ntiles, tile_e, tile_r0,
                                    out + (size_t)N_TOKENS * D_MODEL);
  scatter_kernel<<<N_TOKENS / 256, 256, 0, stream>>>(tok_e, cur, offs, bucket);
  gemm1_kernel<<<(EXPERT_DIM / 64) * MAX_TILES, 256, 0, stream>>>(
      xb, w1, w3, ntiles, tile_e, tile_r0, offs, bucket, H);
  gemm2_kernel<<<(D_MODEL / 64) * MAX_TILES, 256, 0, stream>>>(
      H, w2, ntiles, tile_e, tile_r0, offs, bucket, tok_g, out);
}

// Round 8
// 398.182 us; speedup vs baseline: 1.5606x; 1.5606x over previous
//
#include <hip/hip_runtime.h>
#include <hip/hip_bf16.h>
#include <math.h>

#define D_MODEL    1024
#define EXPERT_DIM 4096
#define N_EXPERTS  8
#define N_TOKENS   4096
#define M_TILE     128
#define MAX_TILES  40
#define KSPLIT     4

typedef __attribute__((ext_vector_type(8))) short short8;
typedef __attribute__((ext_vector_type(4))) float f32x4;

// workspace byte offsets (ws_size >= 243,531,776 proven in R3: bf16w path ran)
#define OFF_PROBS   0u
#define OFF_EXP     131072u
#define OFF_GATE    147456u
#define OFF_CNT     163840u
#define OFF_CUR     163872u
#define OFF_SIMP    163904u
#define OFF_OFFS    163936u
#define OFF_NT      163976u
#define OFF_TE      164096u
#define OFF_TR      164352u
#define OFF_BUCKET  164608u
#define OFF_XB      262144u      // 4096*1024 bf16 = 8 MiB
#define OFF_H       8650752u     // 4096*4096 bf16 = 32 MiB
#define OFF_W1B     42205184u    // 64 MiB bf16 w1
#define OFF_W3B     109314048u   // 64 MiB bf16 w3
#define OFF_W2B     176422912u   // 64 MiB bf16 w2 (ends 243,531,776)
#define OFF_P       OFF_W1B      // fp32 partials alias w1b (dead after gemm1)

#define GLOAD_LDS16(gp, lp) \
  __builtin_amdgcn_global_load_lds((const __attribute__((address_space(1))) void*)(gp), \
                                   (__attribute__((address_space(3))) void*)(lp), 16, 0, 0)

static __device__ __forceinline__ ushort f2b(float f) {
  union { __hip_bfloat16 h; ushort u; } c;
  c.h = __float2bfloat16(f);
  return c.u;
}

static __device__ __forceinline__ short8 pack8(float4 a, float4 b) {
  short8 r;
  r[0] = (short)f2b(a.x); r[1] = (short)f2b(a.y);
  r[2] = (short)f2b(a.z); r[3] = (short)f2b(a.w);
  r[4] = (short)f2b(b.x); r[5] = (short)f2b(b.y);
  r[6] = (short)f2b(b.z); r[7] = (short)f2b(b.w);
  return r;
}

// ---------------- fp32 -> bf16 weight cast ----------------
__global__ __launch_bounds__(256) void cast_kernel(
    const float* __restrict__ src, ushort* __restrict__ dst, int n8) {
  int i = blockIdx.x * blockDim.x + threadIdx.x;
  int stride = gridDim.x * blockDim.x;
  for (; i < n8; i += stride) {
    const float4* s = (const float4*)(src + (size_t)i * 8);
    float4 a = s[0], b = s[1];
    *(short8*)(dst + (size_t)i * 8) = pack8(a, b);
  }
}

// ---------------- gating (fp32, exact argmax) + x -> bf16 cast ----------------
__global__ __launch_bounds__(256) void gate_kernel(
    const float* __restrict__ x, const float* __restrict__ gw,
    float* __restrict__ probs, int* __restrict__ tok_e,
    float* __restrict__ tok_g, int* __restrict__ cnt,
    ushort* __restrict__ xb) {
  int token = (blockIdx.x * blockDim.x + threadIdx.x) >> 6;
  int lane = threadIdx.x & 63;
  if (token >= N_TOKENS) return;
  const float* xr = x + (size_t)token * D_MODEL;
  float xv[16];
#pragma unroll
  for (int i = 0; i < 16; ++i) xv[i] = xr[lane + 64 * i];
  ushort* xo = xb + (size_t)token * D_MODEL;
#pragma unroll
  for (int i = 0; i < 16; ++i) xo[lane + 64 * i] = f2b(xv[i]);
  float logit[N_EXPERTS];
#pragma unroll
  for (int e = 0; e < N_EXPERTS; ++e) {
    const float* g = gw + e * D_MODEL;
    float s = 0.f;
#pragma unroll
    for (int i = 0; i < 16; ++i) s = fmaf(xv[i], g[lane + 64 * i], s);
#pragma unroll
    for (int m = 32; m; m >>= 1) s += __shfl_xor(s, m, 64);
    logit[e] = s;
  }
  if (lane == 0) {
    float mx = logit[0]; int arg = 0;
#pragma unroll
    for (int e = 1; e < N_EXPERTS; ++e)
      if (logit[e] > mx) { mx = logit[e]; arg = e; }
    float pe[N_EXPERTS]; float den = 0.f;
#pragma unroll
    for (int e = 0; e < N_EXPERTS; ++e) { pe[e] = __expf(logit[e] - mx); den += pe[e]; }
    float inv = 1.f / den;
#pragma unroll
    for (int e = 0; e < N_EXPERTS; ++e) probs[token * N_EXPERTS + e] = pe[e] * inv;
    tok_e[token] = arg;
    tok_g[token] = pe[arg] * inv;
    atomicAdd(&cnt[arg], 1);
  }
}

__global__ __launch_bounds__(256) void imp_kernel(
    const float* __restrict__ probs, float* __restrict__ simp) {
  int row = blockIdx.x * 256 + threadIdx.x;
  const float4* p = (const float4*)(probs + (size_t)row * N_EXPERTS);
  float4 a = p[0], b = p[1];
  float v[8] = {a.x, a.y, a.z, a.w, b.x, b.y, b.z, b.w};
#pragma unroll
  for (int m = 32; m; m >>= 1)
#pragma unroll
    for (int i = 0; i < 8; ++i) v[i] += __shfl_xor(v[i], m, 64);
  if ((threadIdx.x & 63) == 0)
#pragma unroll
    for (int i = 0; i < 8; ++i) atomicAdd(&simp[i], v[i]);
}

__global__ void plan_kernel(
    const int* __restrict__ cnt, const float* __restrict__ simp,
    int* __restrict__ offs, int* __restrict__ ntiles,
    int* __restrict__ tile_e, int* __restrict__ tile_r0,
    float* __restrict__ aux_out) {
  if (threadIdx.x == 0 && blockIdx.x == 0) {
    int o = 0, nt = 0; float aux = 0.f;
    for (int e = 0; e < N_EXPERTS; ++e) {
      offs[e] = o;
      int c = cnt[e];
      int m = (c + M_TILE - 1) / M_TILE;
      for (int i = 0; i < m; ++i) { tile_e[nt] = e; tile_r0[nt] = i * M_TILE; ++nt; }
      aux += (float)c * simp[e];
      o += c;
    }
    offs[N_EXPERTS] = o;
    *ntiles = nt;
    *aux_out = aux * (1.f / ((float)N_TOKENS * (float)N_TOKENS)) * N_EXPERTS * 0.01f;
  }
}

__global__ __launch_bounds__(256) void scatter_kernel(
    const int* __restrict__ tok_e, int* __restrict__ cursor,
    const int* __restrict__ offs, int* __restrict__ bucket) {
  int n = blockIdx.x * blockDim.x + threadIdx.x;
  if (n >= N_TOKENS) return;
  int e = tok_e[n];
  int p = atomicAdd(&cursor[e], 1);
  bucket[offs[e] + p] = n;
}

// ---- GEMM1: 128x128 tile, 256 thr, DUAL acc (U=x.w1^T, V=x.w3^T).
// All operands bf16 via global_load_lds; XOR-involution swizzle (R6/R7-verified);
// m97 2-barrier loop; silu fused in epilogue. LDS 48 KB. ----
__global__ __launch_bounds__(256, 2) void gemm1_kernel(
    const ushort* __restrict__ xb, const ushort* __restrict__ w1b,
    const ushort* __restrict__ w3b, const int* __restrict__ ntiles,
    const int* __restrict__ tile_e, const int* __restrict__ tile_r0,
    const int* __restrict__ offs, const int* __restrict__ bucket,
    ushort* __restrict__ H) {
  // nwg = 32 f-panels * 40 tiles = 1280; XCD chunk 160 (4 panels), m-fastest
  int bid = blockIdx.x;
  int wgid = (bid & 7) * 160 + (bid >> 3);
  int fi = wgid / MAX_TILES;
  int tile = wgid % MAX_TILES;
  if (tile >= *ntiles) return;
  int e = tile_e[tile], r0 = tile_r0[tile];
  int base = offs[e], cnt = offs[e + 1] - base;
  int f0 = fi * 128;

  __shared__ ushort As[128 * 64];    // 16 KB each
  __shared__ ushort B1s[128 * 64];
  __shared__ ushort B3s[128 * 64];

  int tid = threadIdx.x;
  int w = tid >> 6, l = tid & 63;
  int wm = w >> 1, wn = w & 1;

  // staging: issue c covers rows c*32 + w*8 + (l>>3); pre-swizzled source col
  const ushort* aptr[4];
  const ushort* b1p[4];
  const ushort* b3p[4];
  int scol = ((l & 7) ^ (l >> 3)) * 8;
#pragma unroll
  for (int c = 0; c < 4; ++c) {
    int r = c * 32 + w * 8 + (l >> 3);
    int rr = min(r0 + r, cnt - 1);
    aptr[c] = xb + (size_t)bucket[base + rr] * D_MODEL + scol;
    b1p[c] = w1b + ((size_t)e * EXPERT_DIM + f0 + r) * D_MODEL + scol;
    b3p[c] = w3b + ((size_t)e * EXPERT_DIM + f0 + r) * D_MODEL + scol;
  }

  f32x4 accU[4][4], accV[4][4];
#pragma unroll
  for (int i = 0; i < 4; ++i)
#pragma unroll
    for (int j = 0; j < 4; ++j) { accU[i][j] = (f32x4)0.f; accV[i][j] = (f32x4)0.f; }

  for (int k = 0; k < 16; ++k) {
    int k0 = k * 64;
#pragma unroll
    for (int c = 0; c < 4; ++c) {
      GLOAD_LDS16(aptr[c] + k0, &As[(c * 32 + w * 8) * 64]);
      GLOAD_LDS16(b1p[c] + k0, &B1s[(c * 32 + w * 8) * 64]);
      GLOAD_LDS16(b3p[c] + k0, &B3s[(c * 32 + w * 8) * 64]);
    }
    __syncthreads();
#pragma unroll
    for (int ks = 0; ks < 2; ++ks) {
      int acol = (ks * 32 + (l >> 4) * 8) ^ ((l & 7) << 3);
      short8 af[4], b1f[4], b3f[4];
#pragma unroll
      for (int i = 0; i < 4; ++i)
        af[i] = *(const short8*)&As[(wm * 64 + i * 16 + (l & 15)) * 64 + acol];
#pragma unroll
      for (int j = 0; j < 4; ++j) {
        b1f[j] = *(const short8*)&B1s[(wn * 64 + j * 16 + (l & 15)) * 64 + acol];
        b3f[j] = *(const short8*)&B3s[(wn * 64 + j * 16 + (l & 15)) * 64 + acol];
      }
#pragma unroll
      for (int i = 0; i < 4; ++i)
#pragma unroll
        for (int j = 0; j < 4; ++j) {
          accU[i][j] = __builtin_amdgcn_mfma_f32_16x16x32_bf16(af[i], b1f[j], accU[i][j], 0, 0, 0);
          accV[i][j] = __builtin_amdgcn_mfma_f32_16x16x32_bf16(af[i], b3f[j], accV[i][j], 0, 0, 0);
        }
    }
    __syncthreads();
  }

  // epilogue: h = silu(u)*v -> bf16 H
#pragma unroll
  for (int i = 0; i < 4; ++i)
#pragma unroll
    for (int q = 0; q < 4; ++q) {
      int m_loc = wm * 64 + i * 16 + (l >> 4) * 4 + q;
      if (r0 + m_loc < cnt) {
        size_t rowb = (size_t)(base + r0 + m_loc) * EXPERT_DIM + f0 + wn * 64 + (l & 15);
#pragma unroll
        for (int j = 0; j < 4; ++j) {
          float uu = accU[i][j][q], vv = accV[i][j][q];
          float hh = uu / (1.f + __expf(-uu)) * vv;
          H[rowb + j * 16] = f2b(hh);
        }
      }
    }
}

// ---- GEMM2: m97-exact 128x128, split-K=4 -> fp32 partials ----
__global__ __launch_bounds__(256, 2) void gemm2_kernel(
    const ushort* __restrict__ H, const ushort* __restrict__ w2b,
    const int* __restrict__ ntiles, const int* __restrict__ tile_e,
    const int* __restrict__ tile_r0, const int* __restrict__ offs,
    float* __restrict__ P) {
  // nwg = 8 d-panels * 40 * 4 kz = 1280; XCD chunk 160 = 1 d-panel
  int bid = blockIdx.x;
  int wgid = (bid & 7) * 160 + (bid >> 3);
  int di = wgid / (MAX_TILES * KSPLIT);
  int rest = wgid % (MAX_TILES * KSPLIT);
  int kz = rest / MAX_TILES;
  int tile = rest % MAX_TILES;
  if (tile >= *ntiles) return;
  int e = tile_e[tile], r0 = tile_r0[tile];
  int base = offs[e], cnt = offs[e + 1] - base;
  int d0 = di * 128;

  __shared__ ushort As[128 * 64];
  __shared__ ushort Bs[128 * 64];

  int tid = threadIdx.x;
  int w = tid >> 6, l = tid & 63;
  int wm = w >> 1, wn = w & 1;

  const ushort* aptr[4];
  const ushort* bp[4];
  int scol = ((l & 7) ^ (l >> 3)) * 8;
#pragma unroll
  for (int c = 0; c < 4; ++c) {
    int r = c * 32 + w * 8 + (l >> 3);
    int rr = min(r0 + r, cnt - 1);
    aptr[c] = H + (size_t)(base + rr) * EXPERT_DIM + kz * (EXPERT_DIM / KSPLIT) + scol;
    bp[c] = w2b + ((size_t)e * D_MODEL + d0 + r) * EXPERT_DIM + kz * (EXPERT_DIM / KSPLIT) + scol;
  }

  f32x4 acc[4][4];
#pragma unroll
  for (int i = 0; i < 4; ++i)
#pragma unroll
    for (int j = 0; j < 4; ++j) acc[i][j] = (f32x4)0.f;

  for (int k = 0; k < 16; ++k) {
    int k0 = k * 64;
#pragma unroll
    for (int c = 0; c < 4; ++c) {
      GLOAD_LDS16(aptr[c] + k0, &As[(c * 32 + w * 8) * 64]);
      GLOAD_LDS16(bp[c] + k0, &Bs[(c * 32 + w * 8) * 64]);
    }
    __syncthreads();
#pragma unroll
    for (int ks = 0; ks < 2; ++ks) {
      int acol = (ks * 32 + (l >> 4) * 8) ^ ((l & 7) << 3);
      short8 af[4], bf[4];
#pragma unroll
      for (int i = 0; i < 4; ++i)
        af[i] = *(const short8*)&As[(wm * 64 + i * 16 + (l & 15)) * 64 + acol];
#pragma unroll
      for (int j = 0; j < 4; ++j)
        bf[j] = *(const short8*)&Bs[(wn * 64 + j * 16 + (l & 15)) * 64 + acol];
#pragma unroll
      for (int i = 0; i < 4; ++i)
#pragma unroll
        for (int j = 0; j < 4; ++j)
          acc[i][j] = __builtin_amdgcn_mfma_f32_16x16x32_bf16(af[i], bf[j], acc[i][j], 0, 0, 0);
    }
    __syncthreads();
  }

#pragma unroll
  for (int i = 0; i < 4; ++i)
#pragma unroll
    for (int q = 0; q < 4; ++q) {
      int r = wm * 64 + i * 16 + (l >> 4) * 4 + q;
      if (r0 + r < cnt) {
        float* pp = P + ((size_t)kz * N_TOKENS + base + r0 + r) * D_MODEL + d0 + wn * 64 + (l & 15);
#pragma unroll
        for (int j = 0; j < 4; ++j)
          pp[j * 16] = acc[i][j][q];
      }
    }
}

// ---- reduce: out[tok] = (sum_kz P[kz][pos]) * gate ----
__global__ __launch_bounds__(256) void reduce_kernel(
    const float* __restrict__ P, const int* __restrict__ bucket,
    const float* __restrict__ tok_g, float* __restrict__ out) {
  int gid = blockIdx.x * 256 + threadIdx.x;
  int pos = gid >> 8;
  int dv = (gid & 255) * 4;
  int tok = bucket[pos];
  float g = tok_g[tok];
  const float* b = P + (size_t)pos * D_MODEL + dv;
  float4 s = *(const float4*)b;
#pragma unroll
  for (int kz = 1; kz < KSPLIT; ++kz) {
    float4 t = *(const float4*)(b + (size_t)kz * N_TOKENS * D_MODEL);
    s.x += t.x; s.y += t.y; s.z += t.z; s.w += t.w;
  }
  float4 r = make_float4(s.x * g, s.y * g, s.z * g, s.w * g);
  *(float4*)(out + (size_t)tok * D_MODEL + dv) = r;
}

extern "C" void kernel_launch(void* const* d_in, const int* in_sizes, int n_in,
                              void* d_out, int out_size, void* d_ws, size_t ws_size,
                              hipStream_t stream) {
  const float* x  = (const float*)d_in[0];
  const float* gw = (const float*)d_in[1];
  const float* w1 = (const float*)d_in[2];
  const float* w2 = (const float*)d_in[3];
  const float* w3 = (const float*)d_in[4];
  float* out = (float*)d_out;
  char* ws = (char*)d_ws;

  float* probs = (float*)(ws + OFF_PROBS);
  int* tok_e   = (int*)(ws + OFF_EXP);
  float* tok_g = (float*)(ws + OFF_GATE);
  int* cnt     = (int*)(ws + OFF_CNT);
  int* cur     = (int*)(ws + OFF_CUR);
  float* simp  = (float*)(ws + OFF_SIMP);
  int* offs    = (int*)(ws + OFF_OFFS);
  int* ntiles  = (int*)(ws + OFF_NT);
  int* tile_e  = (int*)(ws + OFF_TE);
  int* tile_r0 = (int*)(ws + OFF_TR);
  int* bucket  = (int*)(ws + OFF_BUCKET);
  ushort* xb   = (ushort*)(ws + OFF_XB);
  ushort* H    = (ushort*)(ws + OFF_H);
  ushort* w1b  = (ushort*)(ws + OFF_W1B);
  ushort* w3b  = (ushort*)(ws + OFF_W3B);
  ushort* w2b  = (ushort*)(ws + OFF_W2B);
  float* P     = (float*)(ws + OFF_P);

  const int n8 = N_EXPERTS * EXPERT_DIM * D_MODEL / 8;

  hipMemsetAsync(ws + OFF_CNT, 0, 96, stream);  // cnt + cursor + simp
  cast_kernel<<<2048, 256, 0, stream>>>(w1, w1b, n8);
  cast_kernel<<<2048, 256, 0, stream>>>(w3, w3b, n8);
  cast_kernel<<<2048, 256, 0, stream>>>(w2, w2b, n8);
  gate_kernel<<<N_TOKENS / 4, 256, 0, stream>>>(x, gw, probs, tok_e, tok_g, cnt, xb);
  imp_kernel<<<N_TOKENS / 256, 256, 0, stream>>>(probs, simp);
  plan_kernel<<<1, 64, 0, stream>>>(cnt, simp, offs, ntiles, tile_e, tile_r0,
                                    out + (size_t)N_TOKENS * D_MODEL);
  scatter_kernel<<<N_TOKENS / 256, 256, 0, stream>>>(tok_e, cur, offs, bucket);
  gemm1_kernel<<<(EXPERT_DIM / 128) * MAX_TILES, 256, 0, stream>>>(
      xb, w1b, w3b, ntiles, tile_e, tile_r0, offs, bucket, H);
  gemm2_kernel<<<(D_MODEL / 128) * MAX_TILES * KSPLIT, 256, 0, stream>>>(
      H, w2b, ntiles, tile_e, tile_r0, offs, P);
  reduce_kernel<<<N_TOKENS * D_MODEL / 4 / 256, 256, 0, stream>>>(P, bucket, tok_g, out);
}